// Round 9
// baseline (661.536 us; speedup 1.0000x reference)
//
#include <hip/hip_runtime.h>

// 2-layer LSTM (HID=10), B=2048, T=1024 main + F=64 future steps.
// Round 9: back to the P=10 decomposition (r2) with the register lessons of
// r5-r7. Lane (e,u): 10 lanes per element, 6 elements per 64-lane wave,
// 342 single-wave blocks (1 wave/SIMD on 342 of 1024 SIMDs). Each lane owns
// ALL 4 gate rows of its unit -> gates are lane-local (no f/g/o gathers);
// only h-broadcast (10 bperm per cell) crosses lanes. Per-step fixed overhead
// (acts/trans/head/glue) is paid once per SIX elements instead of once per
// element (r3-r8). 6 independent element-chains per wave supply the ILP that
// single-element waves lacked.
//   - amdgpu_waves_per_eu(1,1): 512-VGPR budget for ~190 live floats
//     (r2 failed on VGPR=116 spill shuttle; r5 proved this knob fixes it).
//   - act constants folded per gate row: pre-acts arrive pre-scaled; g-gate
//     scaled by tK so cell state carries tK*c and ctanh needs no mul.
//   - x: per-lane global float4, prefetched one group ahead. Stores: float4
//     by the u==0 lane of each element.

#define NB 2048
#define TMAIN 1024
#define HID 10
#define EPW 6

#define PIN(v) asm volatile("" : "+v"(v))

__device__ __forceinline__ float rcp_(float v)  { return __builtin_amdgcn_rcpf(v); }
__device__ __forceinline__ float exp2_(float v) { return __builtin_amdgcn_exp2f(v); }

__global__ __launch_bounds__(64)
__attribute__((amdgpu_waves_per_eu(1, 1)))
void lstm2_kernel(
    const float* __restrict__ x,
    const float* __restrict__ Wih1, const float* __restrict__ Whh1,
    const float* __restrict__ bih1, const float* __restrict__ bhh1,
    const float* __restrict__ Wih2, const float* __restrict__ Whh2,
    const float* __restrict__ bih2, const float* __restrict__ bhh2,
    const float* __restrict__ Wlin, const float* __restrict__ blin,
    const int* __restrict__ futp,
    float* __restrict__ out)
{
    const int lane = threadIdx.x;
    const int blk  = blockIdx.x;
    const int F    = futp[0];
    const int OUTW = TMAIN + F;

    const float LOG2E = 1.4426950408889634f;
    const float tK    = 2.0f * LOG2E;

    int e_raw = lane / HID;                       // 0..6
    const int u = lane - e_raw * HID;             // 0..9 (0..3 for lanes 60..63)
    const int e = (e_raw < EPW) ? e_raw : 0;      // lanes 60..63 shadow element 0
    const int ge  = blk * EPW + e;
    const int gec = (ge < NB) ? ge : (NB - 1);
    const bool active = (e_raw < EPW) && (ge < NB);
    const int ebase = e * HID;

    int baddr[HID];
    #pragma unroll
    for (int j = 0; j < HID; ++j) baddr[j] = (ebase + j) * 4;

    // ---- per-lane weights: all 4 gate rows of unit u, prescaled per row ----
    // K_k = -log2e for sigmoid gates (i,f,o), +2log2e for g (tanh);
    // act_k = A_k + B_k * rcp(1 + exp2(p));  (A,B) = (0,1) sigmoid,
    // (tK, -2tK) for g  -> g arrives scaled by tK, cell state carries tK*c.
    float w1[4][HID], wi2[4][HID], wh2[4][HID], wx[4], b1[4], b2[4];
    float wl[HID], bl;
    #pragma unroll
    for (int k = 0; k < 4; ++k) {
        const float K = (k == 2) ? tK : -LOG2E;
        const int r = k * HID + u;
        wx[k] = Wih1[r] * K;
        b1[k] = (bih1[r] + bhh1[r]) * K;
        b2[k] = (bih2[r] + bhh2[r]) * K;
        #pragma unroll
        for (int j = 0; j < HID; ++j) {
            w1[k][j]  = Whh1[r * HID + j] * K;
            wi2[k][j] = Wih2[r * HID + j] * K;
            wh2[k][j] = Whh2[r * HID + j] * K;
        }
    }
    #pragma unroll
    for (int j = 0; j < HID; ++j) wl[j] = Wlin[j];
    bl = blin[0];

    #pragma unroll
    for (int k = 0; k < 4; ++k) {
        PIN(wx[k]); PIN(b1[k]); PIN(b2[k]);
        #pragma unroll
        for (int j = 0; j < HID; ++j) { PIN(w1[k][j]); PIN(wi2[k][j]); PIN(wh2[k][j]); }
    }
    #pragma unroll
    for (int j = 0; j < HID; ++j) PIN(wl[j]);
    PIN(bl);

    auto bp = [](int addr, float v) -> float {
        return __int_as_float(__builtin_amdgcn_ds_bpermute(addr, __float_as_int(v)));
    };
    auto act = [&](float p, int k) -> float {       // pre-act arrives prescaled
        const float A = (k == 2) ? tK : 0.0f;
        const float B = (k == 2) ? -2.0f * tK : 1.0f;
        return fmaf(B, rcp_(1.0f + exp2_(p)), A);
    };
    auto ctanh = [&](float cs) -> float {           // cs = tK * c
        return fmaf(-2.0f, rcp_(1.0f + exp2_(cs)), 1.0f);
    };

    // ---- state (per lane: its element's full h vectors + its unit's c) ----
    float c1 = 0.f, c2 = 0.f;
    float h1b[HID], h2b[HID];
    #pragma unroll
    for (int j = 0; j < HID; ++j) { h1b[j] = 0.f; h2b[j] = 0.f; }

    auto step = [&](float xt) -> float {
        float p[4];
        // cell 1: 4 gate pre-acts, 2 chains each
        #pragma unroll
        for (int k = 0; k < 4; ++k) {
            float s0 = fmaf(xt, wx[k], b1[k]);
            float s1 = h1b[5] * w1[k][5];
            #pragma unroll
            for (int j = 0; j < 5; ++j) {
                s0 = fmaf(h1b[j], w1[k][j], s0);
                if (j) s1 = fmaf(h1b[5 + j], w1[k][5 + j], s1);
            }
            p[k] = s0 + s1;
        }
        float gi = act(p[0], 0), gf = act(p[1], 1), gg = act(p[2], 2), go = act(p[3], 3);
        c1 = fmaf(gf, c1, gi * gg);                 // carries tK*c1
        float h1u = go * ctanh(c1);
        #pragma unroll
        for (int j = 0; j < HID; ++j) h1b[j] = bp(baddr[j], h1u);

        // cell 2: 4 gate pre-acts, 4 chains each
        #pragma unroll
        for (int k = 0; k < 4; ++k) {
            float s0 = b2[k];
            float s1 = h1b[5] * wi2[k][5];
            float s2 = h2b[0] * wh2[k][0];
            float s3 = h2b[5] * wh2[k][5];
            #pragma unroll
            for (int j = 0; j < 5; ++j) {
                s0 = fmaf(h1b[j], wi2[k][j], s0);
                if (j) s1 = fmaf(h1b[5 + j], wi2[k][5 + j], s1);
                if (j) s2 = fmaf(h2b[j],     wh2[k][j],     s2);
                if (j) s3 = fmaf(h2b[5 + j], wh2[k][5 + j], s3);
            }
            p[k] = (s0 + s1) + (s2 + s3);
        }
        gi = act(p[0], 0); gf = act(p[1], 1); gg = act(p[2], 2); go = act(p[3], 3);
        c2 = fmaf(gf, c2, gi * gg);                 // carries tK*c2
        float h2u = go * ctanh(c2);
        #pragma unroll
        for (int j = 0; j < HID; ++j) h2b[j] = bp(baddr[j], h2u);

        // head (2 chains)
        float y0 = fmaf(h2b[0], wl[0], bl);
        float y1 = h2b[5] * wl[5];
        #pragma unroll
        for (int j = 1; j < 5; ++j) {
            y0 = fmaf(h2b[j],     wl[j],     y0);
            y1 = fmaf(h2b[5 + j], wl[5 + j], y1);
        }
        return y0 + y1;
    };

    // ---- main loop: 4 steps/group, per-lane x float4 prefetched one ahead ----
    const float4* xrow = (const float4*)(x + (size_t)gec * TMAIN);
    float4* orow = (float4*)(out + (size_t)ge * OUTW);   // OUTW=1088, 16B-aligned
    float4 xv = xrow[0];
    #pragma unroll 1
    for (int t4 = 0; t4 < TMAIN / 4; ++t4) {
        float4 xn = (t4 + 1 < TMAIN / 4) ? xrow[t4 + 1] : make_float4(0.f, 0.f, 0.f, 0.f);
        float4 yv;
        yv.x = step(xv.x);
        yv.y = step(xv.y);
        yv.z = step(xv.z);
        yv.w = step(xv.w);
        if (u == 0 && active) orow[t4] = yv;
        xv = xn;
    }

    // ---- future loop: y feeds back (uniform within each element's lanes) ----
    float yprev;
    {
        float y0 = fmaf(h2b[0], wl[0], bl);
        float y1 = h2b[5] * wl[5];
        #pragma unroll
        for (int j = 1; j < 5; ++j) {
            y0 = fmaf(h2b[j],     wl[j],     y0);
            y1 = fmaf(h2b[5 + j], wl[5 + j], y1);
        }
        yprev = y0 + y1;   // y(TMAIN-1), recomputed cheaply
    }
    int t = 0;
    #pragma unroll 1
    for (; t + 3 < F; t += 4) {
        float y0 = step(yprev);
        float y1 = step(y0);
        float y2 = step(y1);
        float y3 = step(y2);
        if (u == 0 && active) orow[(TMAIN + t) / 4] = make_float4(y0, y1, y2, y3);
        yprev = y3;
    }
    #pragma unroll 1
    for (; t < F; ++t) {
        yprev = step(yprev);
        if (u == 0 && active) out[(size_t)ge * OUTW + TMAIN + t] = yprev;
    }
}

extern "C" void kernel_launch(void* const* d_in, const int* in_sizes, int n_in,
                              void* d_out, int out_size, void* d_ws, size_t ws_size,
                              hipStream_t stream) {
    const float* x    = (const float*)d_in[0];
    const float* Wih1 = (const float*)d_in[1];
    const float* Whh1 = (const float*)d_in[2];
    const float* bih1 = (const float*)d_in[3];
    const float* bhh1 = (const float*)d_in[4];
    const float* Wih2 = (const float*)d_in[5];
    const float* Whh2 = (const float*)d_in[6];
    const float* bih2 = (const float*)d_in[7];
    const float* bhh2 = (const float*)d_in[8];
    const float* Wlin = (const float*)d_in[9];
    const float* blin = (const float*)d_in[10];
    const int*   futp = (const int*)d_in[11];
    float* out = (float*)d_out;

    int grid = (NB + EPW - 1) / EPW;   // 342 single-wave blocks
    lstm2_kernel<<<grid, 64, 0, stream>>>(x, Wih1, Whh1, bih1, bhh1,
                                          Wih2, Whh2, bih2, bhh2,
                                          Wlin, blin, futp, out);
}

// Round 10
// 573.373 us; speedup vs baseline: 1.1538x; 1.1538x over previous
//
#include <hip/hip_runtime.h>

// 2-layer LSTM (HID=10), B=2048, T=1024 main + F=64 future steps.
// Round 10 = r9 (P=10: lane (e,u) owns ALL 4 gate rows of unit u; 6 elements
// per wave; 342 single-wave blocks) + r6's cell pipelining.
//
// Measured basis: r9 busy = 293 cyc/SIMD-step == clean hand count (issue
// economics proven, ~49 cyc/elem), but wall = 1330 (78% stall): one wave/SIMD
// and ONE serial chain per step in the instruction stream (SIMT: the 6
// elements are lanes, not ILP). Fix: cell2(t) || cell1(t+1) are independent
// given h1(t) -> two parallel chains per iteration, ONE batched 20-bperm
// broadcast stage (single lgkmcnt wait), 8 activations in one trans stage.
// Chain/iter ~halves; predicted wall 1330 -> ~650-750.

#define NB 2048
#define TMAIN 1024
#define HID 10
#define EPW 6

#define PIN(v) asm volatile("" : "+v"(v))

__device__ __forceinline__ float rcp_(float v)  { return __builtin_amdgcn_rcpf(v); }
__device__ __forceinline__ float exp2_(float v) { return __builtin_amdgcn_exp2f(v); }

__global__ __launch_bounds__(64)
__attribute__((amdgpu_waves_per_eu(1, 1)))
void lstm2_kernel(
    const float* __restrict__ x,
    const float* __restrict__ Wih1, const float* __restrict__ Whh1,
    const float* __restrict__ bih1, const float* __restrict__ bhh1,
    const float* __restrict__ Wih2, const float* __restrict__ Whh2,
    const float* __restrict__ bih2, const float* __restrict__ bhh2,
    const float* __restrict__ Wlin, const float* __restrict__ blin,
    const int* __restrict__ futp,
    float* __restrict__ out)
{
    const int lane = threadIdx.x;
    const int blk  = blockIdx.x;
    const int F    = futp[0];
    const int OUTW = TMAIN + F;

    const float LOG2E = 1.4426950408889634f;
    const float tK    = 2.0f * LOG2E;

    int e_raw = lane / HID;
    const int u = lane - e_raw * HID;
    const int e = (e_raw < EPW) ? e_raw : 0;      // lanes 60..63 shadow element 0
    const int ge  = blk * EPW + e;
    const int gec = (ge < NB) ? ge : (NB - 1);
    const bool active = (e_raw < EPW) && (ge < NB);
    const int ebase = e * HID;

    int baddr[HID];
    #pragma unroll
    for (int j = 0; j < HID; ++j) baddr[j] = (ebase + j) * 4;

    // ---- per-lane weights: 4 gate rows of unit u, prescaled per row ----
    // sigmoid rows (i,f,o): K=-log2e, act = rcp(1+exp2(p))
    // tanh row (g):         K=+2log2e, act = tK - 2tK*rcp(1+exp2(p))  (carries tK)
    float w1[4][HID], wi2[4][HID], wh2[4][HID], wx[4], b1[4], b2[4];
    float wl[HID], bl;
    #pragma unroll
    for (int k = 0; k < 4; ++k) {
        const float K = (k == 2) ? tK : -LOG2E;
        const int r = k * HID + u;
        wx[k] = Wih1[r] * K;
        b1[k] = (bih1[r] + bhh1[r]) * K;
        b2[k] = (bih2[r] + bhh2[r]) * K;
        #pragma unroll
        for (int j = 0; j < HID; ++j) {
            w1[k][j]  = Whh1[r * HID + j] * K;
            wi2[k][j] = Wih2[r * HID + j] * K;
            wh2[k][j] = Whh2[r * HID + j] * K;
        }
    }
    #pragma unroll
    for (int j = 0; j < HID; ++j) wl[j] = Wlin[j];
    bl = blin[0];

    #pragma unroll
    for (int k = 0; k < 4; ++k) {
        PIN(wx[k]); PIN(b1[k]); PIN(b2[k]);
        #pragma unroll
        for (int j = 0; j < HID; ++j) { PIN(w1[k][j]); PIN(wi2[k][j]); PIN(wh2[k][j]); }
    }
    #pragma unroll
    for (int j = 0; j < HID; ++j) PIN(wl[j]);
    PIN(bl);

    auto bp = [](int addr, float v) -> float {
        return __int_as_float(__builtin_amdgcn_ds_bpermute(addr, __float_as_int(v)));
    };
    auto act = [&](float p, int k) -> float {       // compile-time k => no selects
        if (k == 2) return fmaf(-2.0f * tK, rcp_(1.0f + exp2_(p)), tK);
        return rcp_(1.0f + exp2_(p));
    };
    auto ctanh = [&](float cs) -> float {           // cs = tK*c
        return fmaf(-2.0f, rcp_(1.0f + exp2_(cs)), 1.0f);
    };

    // ---- state: h1b = h1(t), h2b = h2(t-1); c1 = tK*c1(t), c2 = tK*c2(t-1) ----
    float c1 = 0.f, c2 = 0.f;
    float h1b[HID], h2b[HID];
    #pragma unroll
    for (int j = 0; j < HID; ++j) { h1b[j] = 0.f; h2b[j] = 0.f; }

    // cell1 pre-acts from (xt, h1b): 2 chains per gate
    auto cell1_gates = [&](float xt, float (&p)[4]) {
        #pragma unroll
        for (int k = 0; k < 4; ++k) {
            float s0 = fmaf(xt, wx[k], b1[k]);
            float s1 = h1b[5] * w1[k][5];
            #pragma unroll
            for (int j = 0; j < 5; ++j) {
                s0 = fmaf(h1b[j], w1[k][j], s0);
                if (j) s1 = fmaf(h1b[5 + j], w1[k][5 + j], s1);
            }
            p[k] = s0 + s1;
        }
    };
    // cell2 pre-acts from (h1b, h2b): 4 chains per gate
    auto cell2_gates = [&](float (&q)[4]) {
        #pragma unroll
        for (int k = 0; k < 4; ++k) {
            float s0 = b2[k];
            float s1 = h1b[5] * wi2[k][5];
            float s2 = h2b[0] * wh2[k][0];
            float s3 = h2b[5] * wh2[k][5];
            #pragma unroll
            for (int j = 0; j < 5; ++j) {
                s0 = fmaf(h1b[j], wi2[k][j], s0);
                if (j) s1 = fmaf(h1b[5 + j], wi2[k][5 + j], s1);
                if (j) s2 = fmaf(h2b[j],     wh2[k][j],     s2);
                if (j) s3 = fmaf(h2b[5 + j], wh2[k][5 + j], s3);
            }
            q[k] = (s0 + s1) + (s2 + s3);
        }
    };
    auto head = [&]() -> float {
        float y0 = fmaf(h2b[0], wl[0], bl);
        float y1 = h2b[5] * wl[5];
        #pragma unroll
        for (int j = 1; j < 5; ++j) {
            y0 = fmaf(h2b[j],     wl[j],     y0);
            y1 = fmaf(h2b[5 + j], wl[5 + j], y1);
        }
        return y0 + y1;
    };

    // Pipelined iteration t: cell2(t) and cell1(t+1), two parallel chains,
    // one batched broadcast stage. Returns y(t).
    auto pipe_iter = [&](float xnext) -> float {
        float q[4], p[4];
        cell2_gates(q);
        cell1_gates(xnext, p);
        float qi = act(q[0], 0), qf = act(q[1], 1), qg = act(q[2], 2), qo = act(q[3], 3);
        float pi = act(p[0], 0), pf = act(p[1], 1), pg = act(p[2], 2), po = act(p[3], 3);
        c2 = fmaf(qf, c2, qi * qg);
        c1 = fmaf(pf, c1, pi * pg);
        float h2u = qo * ctanh(c2);
        float h1u = po * ctanh(c1);
        #pragma unroll
        for (int j = 0; j < HID; ++j) {
            h2b[j] = bp(baddr[j], h2u);
            h1b[j] = bp(baddr[j], h1u);
        }
        return head();
    };

    // cell2-only (pipeline tail / second half of serial step). Returns y(t).
    auto cell2_only = [&]() -> float {
        float q[4];
        cell2_gates(q);
        float qi = act(q[0], 0), qf = act(q[1], 1), qg = act(q[2], 2), qo = act(q[3], 3);
        c2 = fmaf(qf, c2, qi * qg);
        float h2u = qo * ctanh(c2);
        #pragma unroll
        for (int j = 0; j < HID; ++j) h2b[j] = bp(baddr[j], h2u);
        return head();
    };

    // serial step for the future loop (y feeds back)
    auto fstep = [&](float xt) -> float {
        float p[4];
        cell1_gates(xt, p);
        float pi = act(p[0], 0), pf = act(p[1], 1), pg = act(p[2], 2), po = act(p[3], 3);
        c1 = fmaf(pf, c1, pi * pg);
        float h1u = po * ctanh(c1);
        #pragma unroll
        for (int j = 0; j < HID; ++j) h1b[j] = bp(baddr[j], h1u);
        return cell2_only();
    };

    // ---- prologue: cell1(0) from x[0] (h1 == 0, c1 == 0) ----
    const float4* xrow = (const float4*)(x + (size_t)gec * TMAIN);
    float4* orow = (float4*)(out + (size_t)ge * OUTW);   // OUTW=1088, 16B-aligned
    float4 xv = xrow[0];
    {
        float p[4];
        #pragma unroll
        for (int k = 0; k < 4; ++k) p[k] = fmaf(xv.x, wx[k], b1[k]);
        float pi = act(p[0], 0), pf = act(p[1], 1), pg = act(p[2], 2), po = act(p[3], 3);
        (void)pf;
        c1 = pi * pg;                                     // old c1 == 0
        float h1u = po * ctanh(c1);
        #pragma unroll
        for (int j = 0; j < HID; ++j) h1b[j] = bp(baddr[j], h1u);
    }

    // ---- main loop: 255 groups of 4 pipelined iterations ----
    #pragma unroll 1
    for (int t4 = 0; t4 < TMAIN / 4 - 1; ++t4) {
        float4 xn = xrow[t4 + 1];
        float y0 = pipe_iter(xv.y);
        float y1 = pipe_iter(xv.z);
        float y2 = pipe_iter(xv.w);
        float y3 = pipe_iter(xn.x);
        if (u == 0 && active) orow[t4] = make_float4(y0, y1, y2, y3);
        xv = xn;
    }
    {   // t = 1020..1022 pipelined, t = 1023 cell2-only
        float y0 = pipe_iter(xv.y);
        float y1 = pipe_iter(xv.z);
        float y2 = pipe_iter(xv.w);
        float y3 = cell2_only();
        if (u == 0 && active) orow[TMAIN / 4 - 1] = make_float4(y0, y1, y2, y3);
    }

    // ---- future loop: serial; y uniform within each element's lanes ----
    float yprev = head();
    int t = 0;
    #pragma unroll 1
    for (; t + 3 < F; t += 4) {
        float y0 = fstep(yprev);
        float y1 = fstep(y0);
        float y2 = fstep(y1);
        float y3 = fstep(y2);
        if (u == 0 && active) orow[(TMAIN + t) / 4] = make_float4(y0, y1, y2, y3);
        yprev = y3;
    }
    #pragma unroll 1
    for (; t < F; ++t) {
        yprev = fstep(yprev);
        if (u == 0 && active) out[(size_t)ge * OUTW + TMAIN + t] = yprev;
    }
}

extern "C" void kernel_launch(void* const* d_in, const int* in_sizes, int n_in,
                              void* d_out, int out_size, void* d_ws, size_t ws_size,
                              hipStream_t stream) {
    const float* x    = (const float*)d_in[0];
    const float* Wih1 = (const float*)d_in[1];
    const float* Whh1 = (const float*)d_in[2];
    const float* bih1 = (const float*)d_in[3];
    const float* bhh1 = (const float*)d_in[4];
    const float* Wih2 = (const float*)d_in[5];
    const float* Whh2 = (const float*)d_in[6];
    const float* bih2 = (const float*)d_in[7];
    const float* bhh2 = (const float*)d_in[8];
    const float* Wlin = (const float*)d_in[9];
    const float* blin = (const float*)d_in[10];
    const int*   futp = (const int*)d_in[11];
    float* out = (float*)d_out;

    int grid = (NB + EPW - 1) / EPW;   // 342 single-wave blocks
    lstm2_kernel<<<grid, 64, 0, stream>>>(x, Wih1, Whh1, bih1, bhh1,
                                          Wih2, Whh2, bih2, bhh2,
                                          Wlin, blin, futp, out);
}